// Round 1
// baseline (420.877 us; speedup 1.0000x reference)
//
#include <hip/hip_runtime.h>

#define HIDDEN 2048
#define INTER  5632
#define TOKENS 4096

#define BM 128
#define BN 128
#define BK 64
#define GROUP_N 4

// gemm1 deep-pipeline tile
#define BM1 256
#define BN1 128
#define NT1 (HIDDEN / BK)   // 32 K-tiles

using bf16x8 = __attribute__((ext_vector_type(8))) __bf16;
using f32x4  = __attribute__((ext_vector_type(4))) float;

__device__ __forceinline__ unsigned short f2bf(float f) {
    unsigned int u = __float_as_uint(f);
    u += 0x7FFFu + ((u >> 16) & 1u);
    return (unsigned short)(u >> 16);
}

#define GLDS(gptr, lptr) \
    __builtin_amdgcn_global_load_lds((__attribute__((address_space(1))) void*)(gptr), \
                                     (__attribute__((address_space(3))) void*)(lptr), 16, 0, 0)

// ---------------- prep: dequant (LDS-cached codebook) + cast x ----------------
// R7-verified (-16 us vs divergent-gather version).
__global__ __launch_bounds__(512) void prep_kernel(
        const float* __restrict__ x, unsigned short* __restrict__ xb,
        const int* __restrict__ ig, const float* __restrict__ cbg,
        const float* __restrict__ sg, unsigned short* __restrict__ wg,
        const int* __restrict__ iu, const float* __restrict__ cbu,
        const float* __restrict__ su, unsigned short* __restrict__ wu,
        const int* __restrict__ idn, const float* __restrict__ cbd,
        const float* __restrict__ sd, unsigned short* __restrict__ wd) {
    __shared__ unsigned short cbl[4096 * 8];   // 64 KB bf16 codebook
    const int b = blockIdx.x;
    const int tid = threadIdx.x;

    if (b >= 528) {                            // ---- cast x ----
        int t = (b - 528) * 512 + tid;
        const float4* x4 = (const float4*)x;
        float4 a = x4[2 * t];
        float4 c = x4[2 * t + 1];
        uint4 o;
        o.x = f2bf(a.x) | ((unsigned int)f2bf(a.y) << 16);
        o.y = f2bf(a.z) | ((unsigned int)f2bf(a.w) << 16);
        o.z = f2bf(c.x) | ((unsigned int)f2bf(c.y) << 16);
        o.w = f2bf(c.z) | ((unsigned int)f2bf(c.w) << 16);
        ((uint4*)xb)[t] = o;
        return;
    }

    const int mat = b / 176;
    const int bl  = b % 176;
    const int* idx; const float* cb; const float* scale; unsigned short* w; int ncol8;
    if (mat == 0)      { idx = ig;  cb = cbg; scale = sg; w = wg; ncol8 = HIDDEN / 8; }
    else if (mat == 1) { idx = iu;  cb = cbu; scale = su; w = wu; ncol8 = HIDDEN / 8; }
    else               { idx = idn; cb = cbd; scale = sd; w = wd; ncol8 = INTER / 8; }

#pragma unroll
    for (int i = 0; i < 8; ++i) {
        int r = i * 512 + tid;
        const float4* c4 = (const float4*)(cb + ((size_t)r << 3));
        float4 a = c4[0];
        float4 c = c4[1];
        uint4 o;
        o.x = f2bf(a.x) | ((unsigned int)f2bf(a.y) << 16);
        o.y = f2bf(a.z) | ((unsigned int)f2bf(a.w) << 16);
        o.z = f2bf(c.x) | ((unsigned int)f2bf(c.y) << 16);
        o.w = f2bf(c.z) | ((unsigned int)f2bf(c.w) << 16);
        ((uint4*)cbl)[r] = o;
    }
    __syncthreads();

    const size_t base = (size_t)bl * 8192;
#pragma unroll 2
    for (int i = 0; i < 16; ++i) {
        size_t t = base + i * 512 + tid;
        int id = idx[t];
        float s = scale[t / ncol8];
        const unsigned short* cw = cbl + ((unsigned)id << 3);
        uint4 cv = *(const uint4*)cw;
        unsigned int ww[4];
#pragma unroll
        for (int j = 0; j < 4; ++j) {
            unsigned int pair = (&cv.x)[j];
            float lo = __uint_as_float(pair << 16) * s;
            float hi = __uint_as_float(pair & 0xFFFF0000u) * s;
            ww[j] = f2bf(lo) | ((unsigned int)f2bf(hi) << 16);
        }
        uint4 o = {ww[0], ww[1], ww[2], ww[3]};
        ((uint4*)w)[t] = o;
    }
}

// XOR-swizzled LDS (R2-verified conflict-free with 16x16 fragments);
// group-raster (R5: FETCH -30%).
// R8 lesson: 32x32 MFMA fragments are 4-way bank-conflicted at BK=64
// unpadded — 16x16 is the only conflict-free geometry here.
// R3: (256,3) on gemm1 spills; R4: BK=32 dbuf regressed; R6: barrier-free
// glds->ds_read is hazard-UNSAFE.
// R9 (this round): gemm1 rebuilt as 256x128 / 512-thread / 8-wave
// deep-pipeline (T3+T4+T5): 4 phases per K-tile, raw s_barrier +
// counted vmcnt(8) so next-next-tile staging stays in flight across the
// barrier (never drain vmcnt to 0 in steady state), setprio(1) around
// each 16-MFMA cluster. 128KB LDS double-buffer, 1 block/CU.
__device__ __forceinline__ void decode_block(int bid, int nblocks_m, int nblocks_n,
                                             int* mb, int* nb) {
    int gw = nblocks_m * GROUP_N;
    int group = bid / gw;
    int inb = bid % gw;
    int gn = group * GROUP_N;
    int width = (nblocks_n - gn < GROUP_N) ? (nblocks_n - gn) : GROUP_N;
    *mb = inb / width;
    *nb = gn + inb % width;
}

// ---------------- GEMM1: H = silu(X Wg^T) * (X Wu^T), bf16 out ----------------
__global__ __launch_bounds__(512, 2) void gemm1_kernel(const unsigned short* __restrict__ X,
                                                       const unsigned short* __restrict__ Wg,
                                                       const unsigned short* __restrict__ Wu,
                                                       unsigned short* __restrict__ H) {
    __shared__ unsigned short As[2][BM1 * BK];    // 64 KB
    __shared__ unsigned short Bgs[2][BN1 * BK];   // 32 KB
    __shared__ unsigned short Bus[2][BN1 * BK];   // 32 KB

    const int tid  = threadIdx.x;
    const int lane = tid & 63;
    const int wave = tid >> 6;
    int mb, nb;
    decode_block(blockIdx.x, TOKENS / BM1, INTER / BN1, &mb, &nb);
    const int m0 = mb * BM1;
    const int n0 = nb * BN1;

    // staging geometry: 512 threads, 16B each; srow 0..63; swizzle on the
    // GLOBAL column chunk (pre-swizzled source, LDS stays lane-linear).
    const int srow = tid >> 3;
    const int scol = (tid & 7) << 3;
    const int gcol = (((tid & 7) ^ (srow & 7))) << 3;

    const int wr = wave >> 1;     // 0..3  (M)
    const int wc = wave & 1;      // 0..1  (N)
    const int ln15 = lane & 15;
    const int lq = lane >> 4;
    const int swr = ln15 & 7;

    f32x4 accg[4][4], accu[4][4];
    const f32x4 z = {0.f, 0.f, 0.f, 0.f};
    for (int i = 0; i < 4; ++i)
        for (int j = 0; j < 4; ++j) { accg[i][j] = z; accu[i][j] = z; }

    // 8 GLDS per thread per K-tile: A x4, Bg x2, Bu x2
#define STAGE1(buf, kt) do {                                                        \
        const int k0_ = (kt) * BK;                                                  \
        _Pragma("unroll")                                                           \
        for (int i_ = 0; i_ < 4; ++i_) {                                            \
            const int r_ = i_ * 64 + srow;                                          \
            GLDS(X + (size_t)(m0 + r_) * HIDDEN + k0_ + gcol,                       \
                 &As[buf][r_ * BK + scol]);                                         \
        }                                                                           \
        _Pragma("unroll")                                                           \
        for (int i_ = 0; i_ < 2; ++i_) {                                            \
            const int r_ = i_ * 64 + srow;                                          \
            GLDS(Wg + (size_t)(n0 + r_) * HIDDEN + k0_ + gcol,                      \
                 &Bgs[buf][r_ * BK + scol]);                                        \
            GLDS(Wu + (size_t)(n0 + r_) * HIDDEN + k0_ + gcol,                      \
                 &Bus[buf][r_ * BK + scol]);                                        \
        }                                                                           \
    } while (0)

    // prologue: fill both buffers, wait only for tile 0 (tile 1 stays in flight)
    STAGE1(0, 0);
    STAGE1(1, 1);
    asm volatile("s_waitcnt vmcnt(8)" ::: "memory");
    __builtin_amdgcn_s_barrier();

    for (int t = 0; t < NT1; ++t) {
        const int cur = t & 1;
        bf16x8 af[4], bg[4], bu[4];
#pragma unroll
        for (int ks = 0; ks < 2; ++ks) {
            const int pofs = (((ks * 4 + lq) ^ swr)) << 3;
            // ---- phase G: read A + Bg fragments, MFMA gate ----
#pragma unroll
            for (int im = 0; im < 4; ++im)
                af[im] = *(const bf16x8*)(&As[cur][(wr * 64 + im * 16 + ln15) * BK + pofs]);
#pragma unroll
            for (int in = 0; in < 4; ++in)
                bg[in] = *(const bf16x8*)(&Bgs[cur][(wc * 64 + in * 16 + ln15) * BK + pofs]);
            __builtin_amdgcn_s_barrier();
            asm volatile("s_waitcnt lgkmcnt(0)" ::: "memory");
            __builtin_amdgcn_s_setprio(1);
#pragma unroll
            for (int im = 0; im < 4; ++im)
#pragma unroll
                for (int in = 0; in < 4; ++in)
                    accg[im][in] = __builtin_amdgcn_mfma_f32_16x16x32_bf16(af[im], bg[in], accg[im][in], 0, 0, 0);
            __builtin_amdgcn_s_setprio(0);
            __builtin_amdgcn_s_barrier();
            // ---- phase U: read Bu fragments (A reused), MFMA up ----
#pragma unroll
            for (int in = 0; in < 4; ++in)
                bu[in] = *(const bf16x8*)(&Bus[cur][(wc * 64 + in * 16 + ln15) * BK + pofs]);
            __builtin_amdgcn_s_barrier();
            asm volatile("s_waitcnt lgkmcnt(0)" ::: "memory");
            __builtin_amdgcn_s_setprio(1);
#pragma unroll
            for (int im = 0; im < 4; ++im)
#pragma unroll
                for (int in = 0; in < 4; ++in)
                    accu[im][in] = __builtin_amdgcn_mfma_f32_16x16x32_bf16(af[im], bu[in], accu[im][in], 0, 0, 0);
            __builtin_amdgcn_s_setprio(0);
            __builtin_amdgcn_s_barrier();
        }
        // ---- boundary: all waves done reading buf[cur] (trailing barrier
        // above). Issue tile t+2 into buf[cur]; counted wait for tile t+1
        // (its 8 loads are the oldest outstanding; t+2's 8 stay in flight).
        if (t + 2 < NT1) {
            STAGE1(cur, t + 2);
            asm volatile("s_waitcnt vmcnt(8)" ::: "memory");
            __builtin_amdgcn_s_barrier();
        } else if (t + 1 < NT1) {
            asm volatile("s_waitcnt vmcnt(0)" ::: "memory");
            __builtin_amdgcn_s_barrier();
        }
    }
#undef STAGE1

#pragma unroll
    for (int im = 0; im < 4; ++im)
#pragma unroll
        for (int in = 0; in < 4; ++in) {
            const int row = m0 + wr * 64 + im * 16 + lq * 4;
            const int col = n0 + wc * 64 + in * 16 + ln15;
#pragma unroll
            for (int r = 0; r < 4; ++r) {
                float g = accg[im][in][r];
                float u = accu[im][in][r];
                float h = g * (1.0f / (1.0f + __expf(-g))) * u;
                H[(size_t)(row + r) * INTER + col] = f2bf(h);
            }
        }
}

// ---------------- GEMM2: Out = H Wd^T, fp32 out ----------------
// launch_bounds(256,3): acc is only 64 regs (single output) so ~110 total
// fits the 170-reg budget at 3 waves/EU; LDS 32KB*3=96<=160KB. 3 blocks/CU
// de-phases the barrier-locked stage/compute bursts (R2->R5 mechanism).
__global__ __launch_bounds__(256, 3) void gemm2_kernel(const unsigned short* __restrict__ Hin,
                                                       const unsigned short* __restrict__ Wd,
                                                       float* __restrict__ Out) {
    __shared__ unsigned short As[BM * BK];
    __shared__ unsigned short Bs[BN * BK];

    const int tid  = threadIdx.x;
    const int lane = tid & 63;
    const int wave = tid >> 6;
    int mb, nb;
    decode_block(blockIdx.x, TOKENS / BM, HIDDEN / BN, &mb, &nb);
    const int m0 = mb * BM;
    const int n0 = nb * BN;

    const int srow = tid >> 3;
    const int scol = (tid & 7) << 3;
    const int gcol = (((tid & 7) ^ (srow & 7))) << 3;

    const int wr = wave >> 1;
    const int wc = wave & 1;
    const int ln15 = lane & 15;
    const int lq = lane >> 4;
    const int swr = ln15 & 7;

    f32x4 acc[4][4];
    const f32x4 z = {0.f, 0.f, 0.f, 0.f};
    for (int i = 0; i < 4; ++i)
        for (int j = 0; j < 4; ++j) acc[i][j] = z;

    for (int kt = 0; kt < INTER / BK; ++kt) {
        const int k0 = kt * BK;
        __syncthreads();
#pragma unroll
        for (int i = 0; i < 4; ++i) {
            const int r = i * 32 + srow;
            GLDS(Hin + (size_t)(m0 + r) * INTER + k0 + gcol, As + r * BK + scol);
            GLDS(Wd  + (size_t)(n0 + r) * INTER + k0 + gcol, Bs + r * BK + scol);
        }
        __syncthreads();
#pragma unroll
        for (int ks = 0; ks < 2; ++ks) {
            bf16x8 af[4], bf[4];
            const int pofs = (((ks * 4 + lq) ^ swr)) << 3;
#pragma unroll
            for (int im = 0; im < 4; ++im)
                af[im] = *(const bf16x8*)(As + (wr * 64 + im * 16 + ln15) * BK + pofs);
#pragma unroll
            for (int in = 0; in < 4; ++in)
                bf[in] = *(const bf16x8*)(Bs + (wc * 64 + in * 16 + ln15) * BK + pofs);
#pragma unroll
            for (int im = 0; im < 4; ++im)
#pragma unroll
                for (int in = 0; in < 4; ++in)
                    acc[im][in] = __builtin_amdgcn_mfma_f32_16x16x32_bf16(af[im], bf[in], acc[im][in], 0, 0, 0);
        }
    }

#pragma unroll
    for (int im = 0; im < 4; ++im)
#pragma unroll
        for (int in = 0; in < 4; ++in) {
            const int row = m0 + wr * 64 + im * 16 + lq * 4;
            const int col = n0 + wc * 64 + in * 16 + ln15;
#pragma unroll
            for (int r = 0; r < 4; ++r)
                Out[(size_t)(row + r) * HIDDEN + col] = acc[im][in][r];
        }
}

extern "C" void kernel_launch(void* const* d_in, const int* in_sizes, int n_in,
                              void* d_out, int out_size, void* d_ws, size_t ws_size,
                              hipStream_t stream) {
    (void)in_sizes; (void)n_in; (void)out_size; (void)ws_size;

    const float* x   = (const float*)d_in[0];
    const float* cbg = (const float*)d_in[1];
    const int*   ig  = (const int*)d_in[2];
    const float* sg  = (const float*)d_in[3];
    const float* cbu = (const float*)d_in[4];
    const int*   iu  = (const int*)d_in[5];
    const float* su  = (const float*)d_in[6];
    const float* cbd = (const float*)d_in[7];
    const int*   idn = (const int*)d_in[8];
    const float* sd  = (const float*)d_in[9];
    float* out = (float*)d_out;

    char* p = (char*)d_ws;
    unsigned short* Xb = (unsigned short*)p; p += (size_t)TOKENS * HIDDEN * 2;
    unsigned short* Wg = (unsigned short*)p; p += (size_t)INTER * HIDDEN * 2;
    unsigned short* Wu = (unsigned short*)p; p += (size_t)INTER * HIDDEN * 2;
    unsigned short* Wd = (unsigned short*)p; p += (size_t)HIDDEN * INTER * 2;
    unsigned short* H  = (unsigned short*)p; p += (size_t)TOKENS * INTER * 2;

    prep_kernel<<<dim3(528 + 2048), dim3(512), 0, stream>>>(
        x, Xb, ig, cbg, sg, Wg, iu, cbu, su, Wu, idn, cbd, sd, Wd);

    gemm1_kernel<<<dim3((TOKENS / BM1) * (INTER / BN1)), dim3(512), 0, stream>>>(Xb, Wg, Wu, H);
    gemm2_kernel<<<dim3((TOKENS / BM) * (HIDDEN / BN)), dim3(256), 0, stream>>>(H, Wd, out);
}